// Round 3
// baseline (296.131 us; speedup 1.0000x reference)
//
#include <hip/hip_runtime.h>
#include <hip/hip_fp16.h>
#include <cstdint>
#include <cstddef>

#define QL 16
#define LSH 8192
#define LWK 2048
#define SCALE 0.08838834764831845f  // 1/sqrt(128)

typedef __attribute__((ext_vector_type(8))) short short8;
typedef __attribute__((ext_vector_type(4))) short short4v;
typedef __attribute__((ext_vector_type(4))) float f32x4;
typedef __attribute__((ext_vector_type(8))) unsigned short ushort8v;

#if defined(__has_builtin)
#if __has_builtin(__builtin_amdgcn_mfma_f32_16x16x16bf16_1k)
#define HAVE_MFMA16 1
#endif
#endif

__device__ __forceinline__ unsigned short f2bf(float f) {
  unsigned int u = __float_as_uint(f);
  u += 0x7fffu + ((u >> 16) & 1u);
  return (unsigned short)(u >> 16);
}
__device__ __forceinline__ float bf2f(unsigned short b) {
  return __uint_as_float(((unsigned int)b) << 16);
}

// async global->LDS, 16 B per lane; lds base must be wave-uniform.
__device__ __forceinline__ void gload_lds16(const float* g, float* lds) {
  __builtin_amdgcn_global_load_lds(
      (const __attribute__((address_space(1))) void*)g,
      (__attribute__((address_space(3))) void*)lds, 16, 0, 0);
}

// --- inline-asm global loads: compiler can neither sink them past compute
// --- nor auto-drain them at barriers (we do counted/placed waits manually).
__device__ __forceinline__ void gload_f4(float4& d, const float* p) {
  asm volatile("global_load_dwordx4 %0, %1, off"
               : "=v"(d)
               : "v"((const __attribute__((address_space(1))) float*)p));
}
__device__ __forceinline__ void gload_f1(float& d, const float* p) {
  asm volatile("global_load_dword %0, %1, off"
               : "=v"(d)
               : "v"((const __attribute__((address_space(1))) float*)p));
}
__device__ __forceinline__ void gload_s8(short8& d, const unsigned short* p) {
  asm volatile("global_load_dwordx4 %0, %1, off"
               : "=v"(d)
               : "v"((const __attribute__((address_space(1))) unsigned short*)p));
}

// ---------------------------------------------------------------------------
// Cast fp32 -> bf16 (hidden_states). n4 float4 groups.
// ---------------------------------------------------------------------------
__global__ __launch_bounds__(256) void k_cast(
    const float* __restrict__ in, unsigned short* __restrict__ outp, int n4)
{
  int i = blockIdx.x * 256 + threadIdx.x;
  if (i < n4) {
    float4 v = ((const float4*)in)[i];
    ushort4 p; p.x = f2bf(v.x); p.y = f2bf(v.y); p.z = f2bf(v.z); p.w = f2bf(v.w);
    ((ushort4*)outp)[i] = p;
  }
}

// ---------------------------------------------------------------------------
// out[32 x Ntot] = Xbf @ Wcat^T.
// R3: split-K x4 (grid x2: more block-level parallelism), 2 chunks of 512
// per block. ALL staging (both chunks' W via gload_lds + both A-frag sets)
// issued up-front; vmcnt(16) gates chunk0, vmcnt(0) gates chunk1. Two
// barriers total, no per-chunk drain cycle.
// blockIdx.x = nb*4 + kq; kq k-range 1024. Partials outA..outD.
// ---------------------------------------------------------------------------
__global__ __launch_bounds__(256, 2) void k_gemm4(
    const unsigned short* __restrict__ Xbf,
    const float* __restrict__ W0, const float* __restrict__ W1, const float* __restrict__ W2,
    const float* __restrict__ b0, const float* __restrict__ b1, const float* __restrict__ b2,
    float* __restrict__ outA, float* __restrict__ outB,
    float* __restrict__ outC, float* __restrict__ outD, int Ntot)
{
  __shared__ float Ws[2][16 * 516];   // 2 x 33 KB (one per chunk); Red reuses buf0
  const int bx = blockIdx.x;
  const int n0 = (bx >> 2) * 16;
  const int kq = bx & 3;
  const float* W; const float* bias; int row0;
  if (n0 < 4096)      { W = W0; bias = b0; row0 = n0; }
  else if (n0 < 5120) { W = W1; bias = b1; row0 = n0 - 4096; }
  else                { W = W2; bias = b2; row0 = n0 - 5120; }
  const int t = threadIdx.x;
  const int w_id = t >> 6;
  const int lane = t & 63;
  const int l15 = lane & 15;
  const int quad = lane >> 4;
  const int cb0 = kq * 1024;
  const int wk = w_id * 128;

  f32x4 C0 = {0.f,0.f,0.f,0.f}, C1 = {0.f,0.f,0.f,0.f};
  short8 xa0[2][4], xa1[2][4];   // [chunk][ks]

  // ---- issue ALL memory up front: stage(0), xa(0), stage(1), xa(1) ----
#pragma unroll
  for (int c = 0; c < 2; ++c) {
    const int cbase = cb0 + c * 512;
#pragma unroll
    for (int i = 0; i < 8; ++i) {          // per wave: 8 gload_lds
      int idx = w_id * 8 + i;
      int r = idx >> 1, hh = idx & 1;
      const float* g = W + (size_t)(row0 + r) * 4096 + cbase + hh * 256 + lane * 4;
      gload_lds16(g, &Ws[c][r * 516 + hh * 256]);
    }
#pragma unroll
    for (int ks = 0; ks < 4; ++ks) {
      int ko = wk + ks * 32 + quad * 8;
      gload_s8(xa0[c][ks], Xbf + (size_t)l15 * 4096 + cbase + ko);
      gload_s8(xa1[c][ks], Xbf + (size_t)(16 + l15) * 4096 + cbase + ko);
    }
  }
  __builtin_amdgcn_sched_barrier(0);
#pragma unroll
  for (int c = 0; c < 2; ++c) {
    if (c == 0) asm volatile("s_waitcnt vmcnt(16)" ::: "memory"); // chunk0 done, chunk1 in flight
    else        asm volatile("s_waitcnt vmcnt(0)"  ::: "memory");
    __builtin_amdgcn_sched_barrier(0);
    __builtin_amdgcn_s_barrier();          // all waves' chunk-c staging visible
    __builtin_amdgcn_sched_barrier(0);
    const float* Wsb = Ws[c];
#pragma unroll
    for (int ks = 0; ks < 4; ++ks) {
      int ko = wk + ks * 32 + quad * 8;
      f32x4 wlo = *(const f32x4*)(&Wsb[l15 * 516 + ko]);
      f32x4 whi = *(const f32x4*)(&Wsb[l15 * 516 + ko + 4]);
      short8 bfr;
      bfr[0] = (short)f2bf(wlo[0]); bfr[1] = (short)f2bf(wlo[1]);
      bfr[2] = (short)f2bf(wlo[2]); bfr[3] = (short)f2bf(wlo[3]);
      bfr[4] = (short)f2bf(whi[0]); bfr[5] = (short)f2bf(whi[1]);
      bfr[6] = (short)f2bf(whi[2]); bfr[7] = (short)f2bf(whi[3]);
      C0 = __builtin_amdgcn_mfma_f32_16x16x32_bf16(xa0[c][ks], bfr, C0, 0, 0, 0);
      C1 = __builtin_amdgcn_mfma_f32_16x16x32_bf16(xa1[c][ks], bfr, C1, 0, 0, 0);
    }
  }
  // ---- epilogue: cross-wave reduce via LDS (buf0: its readers are done) ----
  float* Red = &Ws[0][0];
#pragma unroll
  for (int i = 0; i < 4; ++i) {
    Red[w_id * 512 + (quad * 4 + i) * 16 + l15] = C0[i];
    Red[w_id * 512 + 256 + (quad * 4 + i) * 16 + l15] = C1[i];
  }
  __syncthreads();
  float* dst = (kq == 0) ? outA : (kq == 1) ? outB : (kq == 2) ? outC : outD;
#pragma unroll
  for (int e = t; e < 512; e += 256) {
    float s = Red[e] + Red[512 + e] + Red[1024 + e] + Red[1536 + e];
    int m = e >> 4, n = e & 15;
    if (kq == 0 && bias) s += bias[row0 + n];
    dst[(size_t)m * Ntot + n0 + n] = s;
  }
}

// ---------------------------------------------------------------------------
// out = A + B + C + D (float4 groups), split-K x4 combine of the out-proj.
// ---------------------------------------------------------------------------
__global__ __launch_bounds__(256) void k_add(
    const float* __restrict__ A, const float* __restrict__ B,
    const float* __restrict__ C, const float* __restrict__ D,
    float* __restrict__ o, int n4)
{
  int i = blockIdx.x * 256 + threadIdx.x;
  if (i < n4) {
    float4 a = ((const float4*)A)[i], b = ((const float4*)B)[i];
    float4 c = ((const float4*)C)[i], d = ((const float4*)D)[i];
    float4 r;
    r.x = (a.x + b.x) + (c.x + d.x); r.y = (a.y + b.y) + (c.y + d.y);
    r.z = (a.z + b.z) + (c.z + d.z); r.w = (a.w + b.w) + (c.w + d.w);
    ((float4*)o)[i] = r;
  }
}

// ---------------------------------------------------------------------------
// RoPE: rq (3 variants: pos 12304+q / 4112+q / 2048+q, scale folded),
// RoPE'd k_new and v_new, all bf16. qkv = qkvA+qkvB+qkvC+qkvD (split-K x4).
// ---------------------------------------------------------------------------
__global__ __launch_bounds__(256) void k_rope(
    const float* __restrict__ qA, const float* __restrict__ qB,
    const float* __restrict__ qC, const float* __restrict__ qD,
    const float* __restrict__ cosn, const float* __restrict__ sinn,
    unsigned short* __restrict__ rq, unsigned short* __restrict__ knew,
    unsigned short* __restrict__ vnew)
{
  const int g = blockIdx.x * 256 + threadIdx.x;
  const float LOGTH = 9.210340371976184f; // ln(10000)
  if (g < 393216) {                          // rq: [var][w][head][q][d]
    int d = g & 127, q = (g >> 7) & 15, head = (g >> 11) & 31, w = (g >> 16) & 1, var = g >> 17;
    int tok = w * 16 + q;
    int col = head * 128 + d;
    size_t ix = (size_t)tok * 6144 + col;
    float val = (qA[ix] + qB[ix]) + (qC[ix] + qD[ix]);
    size_t ir = (d < 64) ? ix + 64 : ix - 64;
    float rot = (qA[ir] + qB[ir]) + (qC[ir] + qD[ir]);
    if (d < 64) rot = -rot;
    int pos = (var == 0 ? 12304 : (var == 1 ? 4112 : 2048)) + q;
    int i = d & 63;
    float inv = expf(-(float)i * (LOGTH / 64.0f));
    float ang = (float)pos * inv;
    float c = cosf(ang), s = sinf(ang);
    rq[g] = f2bf((val * c + rot * s) * SCALE);
  } else {
    int g2 = g - 393216;
    if (g2 < 65536) {
      int isv = (g2 >= 32768);
      if (isv) g2 -= 32768;
      int d = g2 & 127, q = (g2 >> 7) & 15, h = (g2 >> 11) & 7, w = (g2 >> 14) & 1;
      int tok = w * 16 + q;
      if (isv) {
        size_t ix = (size_t)tok * 6144 + 5120 + h * 128 + d;
        vnew[g2] = f2bf((qA[ix] + qB[ix]) + (qC[ix] + qD[ix]));
      } else {
        size_t ix = (size_t)tok * 6144 + 4096 + h * 128 + d;
        float val = (qA[ix] + qB[ix]) + (qC[ix] + qD[ix]);
        size_t ir = (d < 64) ? ix + 64 : ix - 64;
        float rot = (qA[ir] + qB[ir]) + (qC[ir] + qD[ir]);
        if (d < 64) rot = -rot;
        float c = cosn[tok * 128 + d], s = sinn[tok * 128 + d];
        knew[g2] = f2bf(val * c + rot * s);
      }
    }
  }
}

// ---------------------------------------------------------------------------
// Flash-attention partials, fixed-max softmax, SWAPPED QK operands.
// R3: chunk = 128 keys (2 tiles of 64), grid = 8 heads x 98 chunks = 784
// blocks (was 400) -- block-level parallelism is the latency-hiding engine.
// Single-buffered LDS (36 KB => up to 4 blocks/CU). Tile-1 loads issued
// (inline asm) before tile-0 compute; __syncthreads protects buf reuse.
// Chunks per head: 64 shared(128) + [16 x w0(128) + 1 new(16)] + same w1.
// ---------------------------------------------------------------------------
__global__ __launch_bounds__(512, 2) void k_attn(
    const float* __restrict__ shk, const float* __restrict__ shv,
    const float* __restrict__ w0k, const float* __restrict__ w0v,
    const float* __restrict__ w1k, const float* __restrict__ w1v,
    const unsigned short* __restrict__ rq,
    const unsigned short* __restrict__ knew, const unsigned short* __restrict__ vnew,
    __half* __restrict__ accP, float* __restrict__ lP)
{
  __shared__ alignas(16) unsigned short Ks[64 * 136];    // [key][d] bf16
  __shared__ alignas(16) unsigned short Vts[128 * 72];   // [d][key] bf16
#ifndef HAVE_MFMA16
  __shared__ alignas(16) unsigned short Plds[8 * 16 * 72];
#endif

  const int h = blockIdx.x / 98;
  const int cidx = blockIdx.x % 98;
  int kind, k0, nk; bool is_new;
  if (cidx < 64)      { kind = 0; k0 = cidx * 128; nk = 128; is_new = false; }
  else if (cidx < 81) { int c = cidx - 64; kind = 1; k0 = c * 128; nk = (c == 16) ? 16 : 128; is_new = (c == 16); }
  else                { int c = cidx - 81; kind = 2; k0 = c * 128; nk = (c == 16) ? 16 : 128; is_new = (c == 16); }

  const int t = threadIdx.x;
  const int w_id = t >> 6;        // 0..7
  const int lane = t & 63;
  const int l15 = lane & 15;
  const int quad = lane >> 4;
  const int worker = w_id >> 2;   // 0..1
  const int hq = w_id & 3;        // q-head within kv group
  // staging decompositions (512 threads)
  const int col4 = t & 31;        // K: float4 column within row
  const int rowb = t >> 5;        // K: base row 0..15
  const int dv = t & 127;         // V: d column
  const int tg = t >> 7;          // V: key-row group 0..3

  int var; bool causal;
  if (kind == 0)      { var = 0; causal = false; }
  else if (kind == 1) { var = (worker == 0) ? 2 : 1; causal = (worker == 0); }
  else                { var = (worker == 1) ? 2 : 1; causal = (worker == 1); }

  const float* Ksrc = (kind == 0) ? (shk + (size_t)h * LSH * 128)
                     : (kind == 1) ? (w0k + (size_t)h * LWK * 128)
                                   : (w1k + (size_t)h * LWK * 128);
  const float* Vsrc = (kind == 0) ? (shv + (size_t)h * LSH * 128)
                     : (kind == 1) ? (w0v + (size_t)h * LWK * 128)
                                   : (w1v + (size_t)h * LWK * 128);
  const int wseg = (kind == 2) ? 1 : 0;
  const unsigned short* knsrc = knew + ((size_t)wseg * 8 + h) * 16 * 128;
  const unsigned short* vnsrc = vnew + ((size_t)wseg * 8 + h) * 16 * 128;

  // B-fragment of rq for this wave's head (B[n=q][k=d])
  const int head = h * 4 + hq;
  short8 arq[4];
  {
    const unsigned short* base =
        rq + ((((size_t)var * 2 + worker) * 32 + head) * 16 + l15) * 128 + quad * 8;
#pragma unroll
    for (int ks = 0; ks < 4; ++ks) arq[ks] = *(const short8*)(base + ks * 32);
  }

  float lrow = 0.f;
  f32x4 acc[8];
#pragma unroll
  for (int dt = 0; dt < 8; ++dt) acc[dt] = {0.f,0.f,0.f,0.f};

  // raw fp32 staging registers (asm-defined -> cannot be sunk/drained)
  float4 kf[4];
  float  vf[16];

  const float* kbase = Ksrc + (size_t)(k0 + rowb) * 128 + col4 * 4;
  const float* vbase = Vsrc + (size_t)(k0 + tg * 8) * 128 + dv;

  auto issue_tile = [&](int st) {
    const float* kp = kbase + (size_t)st * 64 * 128;
#pragma unroll
    for (int i = 0; i < 4; ++i) gload_f4(kf[i], kp + (size_t)i * 16 * 128);
    const float* vp = vbase + (size_t)st * 64 * 128;
#pragma unroll
    for (int g = 0; g < 2; ++g)
#pragma unroll
      for (int i = 0; i < 8; ++i)
        gload_f1(vf[g * 8 + i], vp + (size_t)(g * 32 + i) * 128);
  };

  auto lds_write = [&]() {
#pragma unroll
    for (int i = 0; i < 4; ++i) {
      ushort4 p; p.x = f2bf(kf[i].x); p.y = f2bf(kf[i].y);
      p.z = f2bf(kf[i].z); p.w = f2bf(kf[i].w);
      *(ushort4*)(&Ks[(i * 16 + rowb) * 136 + col4 * 4]) = p;
    }
#pragma unroll
    for (int g = 0; g < 2; ++g) {
      ushort8v p;
#pragma unroll
      for (int i = 0; i < 8; ++i) p[i] = f2bf(vf[g * 8 + i]);
      *(ushort8v*)(&Vts[dv * 72 + (g * 4 + tg) * 8]) = p;
    }
  };

  auto compute = [&](int st) {
    // ---- S' = K x Q^T : A = K-frag (m=key), B = rq (n=q) ----
    f32x4 S[4];
#pragma unroll
    for (int nt = 0; nt < 4; ++nt) S[nt] = {0.f,0.f,0.f,0.f};
#pragma unroll
    for (int ks = 0; ks < 4; ++ks)
#pragma unroll
      for (int nt = 0; nt < 4; ++nt) {
        short8 kfr = *(const short8*)(&Ks[(nt * 16 + l15) * 136 + ks * 32 + quad * 8]);
        S[nt] = __builtin_amdgcn_mfma_f32_16x16x32_bf16(kfr, arq[ks], S[nt], 0, 0, 0);
      }
    if (is_new) {
#pragma unroll
      for (int nt = 0; nt < 4; ++nt)
#pragma unroll
        for (int i = 0; i < 4; ++i) {
          int loc = st * 64 + nt * 16 + quad * 4 + i;   // key index
          if (loc >= nk || (causal && loc > l15)) S[nt][i] = -3.0e38f;
        }
    }
    float rs = 0.0f;
#pragma unroll
    for (int nt = 0; nt < 4; ++nt)
#pragma unroll
      for (int i = 0; i < 4; ++i) {
        float p = __expf(fminf(S[nt][i], 60.0f));
        S[nt][i] = p;
        rs += p;
      }
#ifdef HAVE_MFMA16
    short4v pv[4];
#pragma unroll
    for (int nt = 0; nt < 4; ++nt) {
      short4v pp;
      pp[0] = (short)f2bf(S[nt][0]); pp[1] = (short)f2bf(S[nt][1]);
      pp[2] = (short)f2bf(S[nt][2]); pp[3] = (short)f2bf(S[nt][3]);
      pv[nt] = pp;
    }
#else
#pragma unroll
    for (int nt = 0; nt < 4; ++nt)
#pragma unroll
      for (int i = 0; i < 4; ++i)
        Plds[w_id * (16 * 72) + l15 * 72 + nt * 16 + quad * 4 + i] = f2bf(S[nt][i]);
#endif
    // denominator: sum across quads (keys); q = l15 fixed per lane
    rs += __shfl_xor(rs, 16, 64);
    rs += __shfl_xor(rs, 32, 64);
    lrow += rs;

    // ---- PV ----
#ifdef HAVE_MFMA16
#pragma unroll
    for (int dt = 0; dt < 8; ++dt)
#pragma unroll
      for (int kc = 0; kc < 4; ++kc) {
        short4v vfr = *(const short4v*)(&Vts[(dt * 16 + l15) * 72 + kc * 16 + quad * 4]);
        acc[dt] = __builtin_amdgcn_mfma_f32_16x16x16bf16_1k(pv[kc], vfr, acc[dt], 0, 0, 0);
      }
#else
    short8 ap[2];
#pragma unroll
    for (int ks2 = 0; ks2 < 2; ++ks2)
      ap[ks2] = *(const short8*)(
          &Plds[w_id * (16 * 72) + l15 * 72 + ks2 * 32 + quad * 8]);
#pragma unroll
    for (int dt = 0; dt < 8; ++dt)
#pragma unroll
      for (int ks2 = 0; ks2 < 2; ++ks2) {
        short8 vfr = *(const short8*)(&Vts[(dt * 16 + l15) * 72 + ks2 * 32 + quad * 8]);
        acc[dt] = __builtin_amdgcn_mfma_f32_16x16x32_bf16(ap[ks2], vfr, acc[dt], 0, 0, 0);
      }
#endif
  };

  const int nst = (nk == 16) ? 1 : 2;
  if (!is_new) {
    issue_tile(0);
  } else {
    // 16 new tokens, bf16 source (plain loads; nst==1 so no pipelining).
    // Clamp rows (&15); garbage rows are killed by the score mask.
#pragma unroll
    for (int i = 0; i < 4; ++i) {
      ushort4 p = *(const ushort4*)(knsrc + (size_t)((i * 16 + rowb) & 15) * 128 + col4 * 4);
      kf[i].x = bf2f(p.x); kf[i].y = bf2f(p.y);
      kf[i].z = bf2f(p.z); kf[i].w = bf2f(p.w);
    }
#pragma unroll
    for (int g = 0; g < 2; ++g)
#pragma unroll
      for (int i = 0; i < 8; ++i)
        vf[g * 8 + i] = bf2f(vnsrc[(size_t)((g * 32 + tg * 8 + i) & 15) * 128 + dv]);
  }

  // ---- phase A: tile 0 ----
  asm volatile("s_waitcnt vmcnt(0)" ::: "memory");   // my tile-0 loads done
  __builtin_amdgcn_sched_barrier(0);
  lds_write();
  if (nst > 1) issue_tile(1);                        // in flight across compute(0)
  asm volatile("s_waitcnt lgkmcnt(0)" ::: "memory"); // my ds_writes visible
  __builtin_amdgcn_sched_barrier(0);
  __builtin_amdgcn_s_barrier();                      // raw: no vmcnt drain
  __builtin_amdgcn_sched_barrier(0);
  compute(0);

  // ---- phase B: tile 1 ----
  if (nst > 1) {
    __syncthreads();                                 // buf reuse guard (drains vmcnt too)
    asm volatile("s_waitcnt vmcnt(0)" ::: "memory"); // belt & braces for asm loads
    __builtin_amdgcn_sched_barrier(0);
    lds_write();
    asm volatile("s_waitcnt lgkmcnt(0)" ::: "memory");
    __builtin_amdgcn_sched_barrier(0);
    __builtin_amdgcn_s_barrier();
    __builtin_amdgcn_sched_barrier(0);
    compute(1);
  }

  // ---- write partials (acc layout: row = q = quad*4+i, col = d = dt*16+l15)
  __half* accB = accP + (size_t)blockIdx.x * 128 * 128;
  const int wrow = worker * 64 + hq * 16;
#pragma unroll
  for (int dt = 0; dt < 8; ++dt)
#pragma unroll
    for (int i = 0; i < 4; ++i) {
      int row = wrow + quad * 4 + i;
      int d = dt * 16 + l15;
      accB[row * 128 + d] = __float2half(acc[dt][i]);
    }
  if (quad == 0) {
    int row = wrow + l15;    // q = l15
    lP[(size_t)blockIdx.x * 128 + row] = lrow;
  }
}

// ---------------------------------------------------------------------------
// Combine 98 chunk-partials per (head,row): plain sums (fixed-max softmax).
// ---------------------------------------------------------------------------
__global__ __launch_bounds__(128) void k_combine(
    const __half* __restrict__ accP, const float* __restrict__ lP,
    unsigned short* __restrict__ attnX)
{
  __shared__ float sl[98];
  const int h = blockIdx.x >> 7;
  const int r = blockIdx.x & 127;
  const int d = threadIdx.x;
  if (d < 98) sl[d] = lP[(size_t)(h * 98 + d) * 128 + r];
  __syncthreads();
  float L = 0.0f, A = 0.0f;
#pragma unroll
  for (int c = 0; c < 98; ++c) L += sl[c];
#pragma unroll
  for (int cc = 0; cc < 98; cc += 7) {
    float p[7];
#pragma unroll
    for (int i = 0; i < 7; ++i)
      p[i] = __half2float(accP[((size_t)(h * 98 + cc + i) * 128 + r) * 128 + d]);
#pragma unroll
    for (int i = 0; i < 7; ++i) A += p[i];
  }
  int workerv = r >> 6, hqv = (r >> 4) & 3, q = r & 15;
  int head = h * 4 + hqv;
  attnX[(size_t)(workerv * 16 + q) * 4096 + head * 128 + d] = f2bf(A / L);
}

// ---------------------------------------------------------------------------
extern "C" void kernel_launch(void* const* d_in, const int* in_sizes, int n_in,
                              void* d_out, int out_size, void* d_ws, size_t ws_size,
                              hipStream_t stream)
{
  const float* hs   = (const float*)d_in[0];
  const float* Wq   = (const float*)d_in[1];
  const float* bq   = (const float*)d_in[2];
  const float* Wk   = (const float*)d_in[3];
  const float* bk   = (const float*)d_in[4];
  const float* Wv   = (const float*)d_in[5];
  const float* bv   = (const float*)d_in[6];
  const float* Wo   = (const float*)d_in[7];
  const float* shk  = (const float*)d_in[8];
  const float* shv  = (const float*)d_in[9];
  const float* w0k  = (const float*)d_in[10];
  const float* w0v  = (const float*)d_in[11];
  const float* w1k  = (const float*)d_in[12];
  const float* w1v  = (const float*)d_in[13];
  const float* cosn = (const float*)d_in[14];
  const float* sinn = (const float*)d_in[15];
  float* out = (float*)d_out;

  char* ws = (char*)d_ws;
  // persistent through attn:
  unsigned short* rq     = (unsigned short*)(ws + 0);       // 786432 B
  unsigned short* knew   = (unsigned short*)(ws + 786432);  // 65536
  unsigned short* vnew   = (unsigned short*)(ws + 851968);  // 65536
  unsigned short* hsbf   = (unsigned short*)(ws + 917504);  // 262144
  unsigned short* attnXb = (unsigned short*)(ws + 1179648); // 262144
  float*          lP     = (float*)(ws + 1441792);          // 784*128*4 = 401408
  // accP: 784*128*128*2 = 25,690,112 B @ 1843200 (ends 27,533,312)
  __half*         accP   = (__half*)(ws + 1843200);
  // qkv split-K partials overlay accP region (dead once k_rope is done;
  // accP written only later by k_attn):
  float*          qkvA   = (float*)(ws + 1843200);
  float*          qkvB   = (float*)(ws + 1843200 + 786432);
  float*          qkvC   = (float*)(ws + 1843200 + 2 * 786432);
  float*          qkvD   = (float*)(ws + 1843200 + 3 * 786432);
  // out-proj partials overlay accP too (accP dead after k_combine):
  float*          outA   = (float*)(ws + 1843200);
  float*          outB   = (float*)(ws + 1843200 + 524288);
  float*          outC   = (float*)(ws + 1843200 + 2 * 524288);
  float*          outD   = (float*)(ws + 1843200 + 3 * 524288);

  // 1. cast hidden_states to bf16
  k_cast<<<128, 256, 0, stream>>>(hs, hsbf, 32768);
  // 2. QKV projection, split-K x4 (bias in kq==0 partial)
  k_gemm4<<<1536, 256, 0, stream>>>(hsbf, Wq, Wk, Wv, bq, bk, bv,
                                    qkvA, qkvB, qkvC, qkvD, 6144);
  // 3. RoPE (q x 3 variants + k_new) + v_new, bf16 (sums 4 partials)
  k_rope<<<1792, 256, 0, stream>>>(qkvA, qkvB, qkvC, qkvD, cosn, sinn, rq, knew, vnew);
  // 4. flash-attention partials over 8 heads x 98 key-chunks (512 thr)
  k_attn<<<784, 512, 0, stream>>>(shk, shv, w0k, w0v, w1k, w1v, rq, knew, vnew, accP, lP);
  // 5. combine partials -> attnX (bf16)
  k_combine<<<1024, 128, 0, stream>>>(accP, lP, attnXb);
  // 6. output projection, split-K x4
  k_gemm4<<<1024, 256, 0, stream>>>(attnXb, Wo, Wo, Wo, nullptr, nullptr, nullptr,
                                    outA, outB, outC, outD, 4096);
  // 7. sum quarters -> d_out
  k_add<<<128, 256, 0, stream>>>(outA, outB, outC, outD, out, 32768);
}